// Round 1
// baseline (571.580 us; speedup 1.0000x reference)
//
#include <hip/hip_runtime.h>
#include <math.h>

#define EPS 1e-12f
constexpr int N_ROWS = 262144;
constexpr int KCODES = 1024;
constexpr int DIM    = 64;
constexpr int TM     = 128;   // rows per block
constexpr int KC     = 128;   // codes per LDS chunk
constexpr int LSTR   = 68;    // LDS row stride in floats (16B aligned, bank-spread)
constexpr int NBLK   = N_ROWS / TM;  // 2048

// ---------- prep: normalize codebook, compute ||cn||^2 ----------
__global__ __launch_bounds__(64)
void vq_prep(const float* __restrict__ cb, float* __restrict__ cn, float* __restrict__ cc) {
    int k = blockIdx.x;      // 1024 blocks
    int d = threadIdx.x;     // 64 threads = one wave
    float v = cb[k * DIM + d];
    float s = v * v;
    #pragma unroll
    for (int off = 32; off; off >>= 1) s += __shfl_xor(s, off, 64);
    float vn = v / fmaxf(sqrtf(s), EPS);   // match F.normalize: divide by clamped norm
    cn[k * DIM + d] = vn;
    float s2 = vn * vn;
    #pragma unroll
    for (int off = 32; off; off >>= 1) s2 += __shfl_xor(s2, off, 64);
    if (d == 0) cc[k] = s2;
}

// ---------- main: distances + argmin + gather + per-block loss partial ----------
__global__ __launch_bounds__(256, 2)
void vq_main(const float* __restrict__ x, const float* __restrict__ cb,
             const float* __restrict__ cn, const float* __restrict__ cc,
             float* __restrict__ out_q, float* __restrict__ out_idx,
             float* __restrict__ partial) {
    __shared__ float xs[TM * LSTR];    // raw x tile
    __shared__ float cs[KC * LSTR];    // normalized codebook chunk
    __shared__ float invn[TM];
    __shared__ int   ridx[TM];
    __shared__ float red[4];

    const int tid  = threadIdx.x;
    const int row0 = blockIdx.x * TM;
    const int rg   = tid >> 4;   // 0..15 : row group (rows rg + 16*i)
    const int cg   = tid & 15;   // 0..15 : code group (codes cg + 16*j)

    // --- load x tile: 128 rows x 64 floats, contiguous = 2048 float4 ---
    {
        const float4* xg = (const float4*)x;
        #pragma unroll
        for (int i = 0; i < 8; ++i) {
            int f = tid + 256 * i;            // 0..2047
            int r = f >> 4, c4 = f & 15;
            float4 v = xg[(size_t)row0 * 16 + f];
            *(float4*)&xs[r * LSTR + c4 * 4] = v;
        }
    }
    __syncthreads();

    // --- per-row inverse norms (2 threads per row) ---
    {
        int r = tid >> 1, h = tid & 1;
        float s = 0.f;
        const float4* xr = (const float4*)&xs[r * LSTR + h * 32];
        #pragma unroll
        for (int i = 0; i < 8; ++i) {
            float4 v = xr[i];
            s += v.x * v.x + v.y * v.y + v.z * v.z + v.w * v.w;
        }
        s += __shfl_xor(s, 1, 64);
        if (h == 0) invn[r] = 1.0f / fmaxf(sqrtf(s), EPS);
    }

    float best[8];
    int   bidx[8];
    #pragma unroll
    for (int i = 0; i < 8; ++i) { best[i] = 1e30f; bidx[i] = 0; }

    for (int kc = 0; kc < KCODES / KC; ++kc) {
        __syncthreads();
        // stage codebook chunk into LDS
        {
            const float4* cg4 = (const float4*)(cn + (size_t)kc * KC * DIM);
            #pragma unroll
            for (int i = 0; i < 8; ++i) {
                int f = tid + 256 * i;
                int r = f >> 4, c4 = f & 15;
                float4 v = cg4[f];
                *(float4*)&cs[r * LSTR + c4 * 4] = v;
            }
        }
        float ccv[8];
        #pragma unroll
        for (int j = 0; j < 8; ++j) ccv[j] = cc[kc * KC + cg + 16 * j];
        __syncthreads();

        float acc[8][8];
        #pragma unroll
        for (int i = 0; i < 8; ++i)
            #pragma unroll
            for (int j = 0; j < 8; ++j) acc[i][j] = 0.f;

        #pragma unroll 2
        for (int d4 = 0; d4 < 16; ++d4) {
            float4 xv[8];
            #pragma unroll
            for (int i = 0; i < 8; ++i)
                xv[i] = *(const float4*)&xs[(rg + 16 * i) * LSTR + d4 * 4];
            #pragma unroll
            for (int j = 0; j < 8; ++j) {
                float4 cv = *(const float4*)&cs[(cg + 16 * j) * LSTR + d4 * 4];
                #pragma unroll
                for (int i = 0; i < 8; ++i) {
                    acc[i][j] = fmaf(xv[i].x, cv.x, acc[i][j]);
                    acc[i][j] = fmaf(xv[i].y, cv.y, acc[i][j]);
                    acc[i][j] = fmaf(xv[i].z, cv.z, acc[i][j]);
                    acc[i][j] = fmaf(xv[i].w, cv.w, acc[i][j]);
                }
            }
        }

        // dist = ||cn||^2 - 2 * (x.cn)/||x|| ; per-thread codes visit ascending
        #pragma unroll
        for (int i = 0; i < 8; ++i) {
            float inv = invn[rg + 16 * i];
            #pragma unroll
            for (int j = 0; j < 8; ++j) {
                float dist = ccv[j] - 2.0f * (inv * acc[i][j]);
                int kidx = kc * KC + cg + 16 * j;
                if (dist < best[i]) { best[i] = dist; bidx[i] = kidx; }
            }
        }
    }

    // --- argmin across the 16 cg lanes (lowest-index tie-break like np.argmin) ---
    #pragma unroll
    for (int i = 0; i < 8; ++i) {
        float d = best[i]; int ix = bidx[i];
        #pragma unroll
        for (int off = 1; off < 16; off <<= 1) {
            float d2 = __shfl_xor(d, off, 64);
            int   i2 = __shfl_xor(ix, off, 64);
            if (d2 < d || (d2 == d && i2 < ix)) { d = d2; ix = i2; }
        }
        if (cg == 0) ridx[rg + 16 * i] = ix;
    }
    __syncthreads();

    // indices out (as float)
    if (tid < TM) out_idx[row0 + tid] = (float)ridx[tid];

    // --- gather quantized (UN-normalized codebook), loss partial ---
    float lsum = 0.f;
    #pragma unroll
    for (int i = 0; i < 8; ++i) {
        int f = tid + 256 * i;           // 0..2047 float4s
        int r = f >> 4, c4 = f & 15;
        int idx = ridx[r];
        float4 q  = *(const float4*)(cb + idx * DIM + c4 * 4);
        float4 xv = *(const float4*)&xs[r * LSTR + c4 * 4];
        float dx = q.x - xv.x, dy = q.y - xv.y, dz = q.z - xv.z, dw = q.w - xv.w;
        lsum += dx * dx + dy * dy + dz * dz + dw * dw;
        ((float4*)out_q)[(size_t)row0 * 16 + f] = q;
    }
    #pragma unroll
    for (int off = 32; off; off >>= 1) lsum += __shfl_xor(lsum, off, 64);
    if ((tid & 63) == 0) red[tid >> 6] = lsum;
    __syncthreads();
    if (tid == 0) partial[blockIdx.x] = red[0] + red[1] + red[2] + red[3];
}

// ---------- final: reduce partials -> both losses ----------
__global__ __launch_bounds__(256)
void vq_final(const float* __restrict__ partial, float* __restrict__ out_loss) {
    float s = 0.f;
    for (int i = threadIdx.x; i < NBLK; i += 256) s += partial[i];
    #pragma unroll
    for (int off = 32; off; off >>= 1) s += __shfl_xor(s, off, 64);
    __shared__ float red[4];
    if ((threadIdx.x & 63) == 0) red[threadIdx.x >> 6] = s;
    __syncthreads();
    if (threadIdx.x == 0) {
        float t = red[0] + red[1] + red[2] + red[3];
        float m = t / (float)((size_t)N_ROWS * DIM);
        out_loss[0] = m;   // codebook_loss
        out_loss[1] = m;   // commitment_loss (same forward value)
    }
}

extern "C" void kernel_launch(void* const* d_in, const int* in_sizes, int n_in,
                              void* d_out, int out_size, void* d_ws, size_t ws_size,
                              hipStream_t stream) {
    const float* x  = (const float*)d_in[0];   // [262144, 64]
    const float* cb = (const float*)d_in[1];   // [1024, 64]
    float* out = (float*)d_out;
    // out layout: [N*D quantized][loss][loss][N indices-as-float]
    float* out_q    = out;
    float* out_loss = out + (size_t)N_ROWS * DIM;
    float* out_idx  = out_loss + 2;

    float* cn      = (float*)d_ws;           // 65536 floats
    float* cc      = cn + KCODES * DIM;      // 1024 floats
    float* partial = cc + KCODES;            // 2048 floats

    vq_prep<<<KCODES, 64, 0, stream>>>(cb, cn, cc);
    vq_main<<<NBLK, 256, 0, stream>>>(x, cb, cn, cc, out_q, out_idx, partial);
    vq_final<<<1, 256, 0, stream>>>(partial, out_loss);
}

// Round 2
// 359.197 us; speedup vs baseline: 1.5913x; 1.5913x over previous
//
#include <hip/hip_runtime.h>
#include <math.h>

#define EPS 1e-12f
constexpr int N_ROWS = 262144;
constexpr int KCODES = 1024;
constexpr int DIM    = 64;
constexpr float TAU  = 2e-4f;   // flag threshold: ~7x worst-case bf16x2 error
constexpr int CAP    = 32768;   // recheck list capacity (~23x expected count)

typedef __attribute__((ext_vector_type(8)))  short  short8;
typedef __attribute__((ext_vector_type(16))) float  float16;

__device__ inline unsigned short f2bf(float f) {
    unsigned int u = __float_as_uint(f);
    u = u + 0x7fff + ((u >> 16) & 1);           // RNE
    return (unsigned short)(u >> 16);
}
__device__ inline float bf2f(unsigned short s) {
    return __uint_as_float(((unsigned int)s) << 16);
}

// ---------- K1: normalize codebook, ||cn||^2, bf16 hi/lo in MFMA-frag order ----------
// Frag layout (B-operand, 32x32x16): lane l holds B[k=16s+8*(l>>5)+j][n=32*(4c+t)+(l&31)]
// global buffer: ushort idx = (((c*4+t)*4+s)*2+p)*512 + lane*8 + j   (p: 0=hi,1=lo)
__global__ __launch_bounds__(64)
void vq_prep(const float* __restrict__ cb, float* __restrict__ cn,
             float* __restrict__ cc, unsigned short* __restrict__ frag,
             int* __restrict__ cnt) {
    int n = blockIdx.x;      // code
    int d = threadIdx.x;     // dim
    float v = cb[n * DIM + d];
    float s = v * v;
    #pragma unroll
    for (int off = 32; off; off >>= 1) s += __shfl_xor(s, off, 64);
    float vn = v / fmaxf(sqrtf(s), EPS);
    cn[n * DIM + d] = vn;
    float s2 = vn * vn;
    #pragma unroll
    for (int off = 32; off; off >>= 1) s2 += __shfl_xor(s2, off, 64);
    if (d == 0) cc[n] = s2;
    unsigned short hi = f2bf(vn);
    unsigned short lo = f2bf(vn - bf2f(hi));
    int c = n >> 7, t = (n >> 5) & 3;
    int lane = (n & 31) + 32 * ((d >> 3) & 1);
    int si = d >> 4, j = d & 7;
    size_t base = (size_t)(((c * 4 + t) * 4 + si) * 2) * 512 + lane * 8 + j;
    frag[base]       = hi;
    frag[base + 512] = lo;
    if (n == 0 && d == 0) *cnt = 0;
}

// ---------- K2: MFMA distance + min1/min2/argmin ----------
__global__ __launch_bounds__(256, 3)
void vq_mfma(const float* __restrict__ x, const unsigned short* __restrict__ frag,
             const float* __restrict__ cc, float* __restrict__ out_idx,
             int* __restrict__ cnt, int* __restrict__ list) {
    __shared__ unsigned short Blds[16384];   // 32KB: one 128-code chunk, hi+lo, frag order
    const int tid = threadIdx.x;
    const int w = tid >> 6, l = tid & 63;
    const int lc = l & 31, h = l >> 5;
    const int row = blockIdx.x * 128 + w * 32 + lc;   // A-operand row for this lane

    // --- A: load 32 floats/lane from global, row norm via shfl, bf16 hi/lo split ---
    float xv[4][8];
    float ss = 0.f;
    #pragma unroll
    for (int s = 0; s < 4; ++s) {
        const float* p = x + (size_t)row * DIM + s * 16 + h * 8;
        float4 a = *(const float4*)p;
        float4 b = *(const float4*)(p + 4);
        xv[s][0]=a.x; xv[s][1]=a.y; xv[s][2]=a.z; xv[s][3]=a.w;
        xv[s][4]=b.x; xv[s][5]=b.y; xv[s][6]=b.z; xv[s][7]=b.w;
        ss += a.x*a.x + a.y*a.y + a.z*a.z + a.w*a.w
            + b.x*b.x + b.y*b.y + b.z*b.z + b.w*b.w;
    }
    ss += __shfl_xor(ss, 32, 64);
    float inv = 1.0f / fmaxf(sqrtf(ss), EPS);
    short8 ahi[4], alo[4];
    #pragma unroll
    for (int s = 0; s < 4; ++s)
        #pragma unroll
        for (int j = 0; j < 8; ++j) {
            float v = xv[s][j] * inv;
            unsigned short hb = f2bf(v);
            unsigned short lb = f2bf(v - bf2f(hb));
            ahi[s][j] = (short)hb;
            alo[s][j] = (short)lb;
        }

    float m1[16], m2[16]; int bidx[16];
    #pragma unroll
    for (int r = 0; r < 16; ++r) { m1[r] = INFINITY; m2[r] = INFINITY; bidx[r] = 0; }

    for (int c = 0; c < 8; ++c) {
        __syncthreads();
        // stage 32KB chunk: per wave 8 x 1KB via global_load_lds (lane-linear)
        {
            const unsigned short* g = frag + (size_t)c * 16384 + (w * 8) * 512 + l * 8;
            #pragma unroll
            for (int q = 0; q < 8; ++q) {
                __builtin_amdgcn_global_load_lds(
                    (const __attribute__((address_space(1))) unsigned int*)(g + q * 512),
                    (__attribute__((address_space(3))) unsigned int*)&Blds[(w * 8 + q) * 512],
                    16, 0, 0);
            }
        }
        __syncthreads();
        #pragma unroll
        for (int t = 0; t < 4; ++t) {
            float16 acc = {};
            #pragma unroll
            for (int s = 0; s < 4; ++s) {
                short8 bhi = *((const short8*)&Blds[((t * 4 + s) * 2    ) * 512] + l);
                short8 blo = *((const short8*)&Blds[((t * 4 + s) * 2 + 1) * 512] + l);
                acc = __builtin_amdgcn_mfma_f32_32x32x16_bf16(ahi[s], bhi, acc, 0, 0, 0);
                acc = __builtin_amdgcn_mfma_f32_32x32x16_bf16(alo[s], bhi, acc, 0, 0, 0);
                acc = __builtin_amdgcn_mfma_f32_32x32x16_bf16(ahi[s], blo, acc, 0, 0, 0);
            }
            int code = c * 128 + t * 32 + lc;
            float cct = cc[code];
            #pragma unroll
            for (int r = 0; r < 16; ++r) {
                float dd = fmaf(-2.0f, acc[r], cct);
                m2[r] = fminf(m2[r], fmaxf(dd, m1[r]));
                if (dd < m1[r]) { m1[r] = dd; bidx[r] = code; }   // ascending code order
            }
        }
    }

    // --- cross-lane argmin over the 32 col-lanes (np first-index tie-break) ---
    #pragma unroll
    for (int r = 0; r < 16; ++r) {
        float d = m1[r], d2 = m2[r]; int ix = bidx[r];
        #pragma unroll
        for (int off = 1; off < 32; off <<= 1) {
            float od  = __shfl_xor(d,  off, 64);
            float od2 = __shfl_xor(d2, off, 64);
            int   oix = __shfl_xor(ix, off, 64);
            float nm2 = fminf(fminf(d2, od2), fmaxf(d, od));
            if (od < d || (od == d && oix < ix)) { d = od; ix = oix; }
            d2 = nm2;
        }
        if (lc == 0) {
            int rr = (r & 3) + 8 * (r >> 2) + 4 * h;      // C/D row map (m74/m101)
            int grow = blockIdx.x * 128 + w * 32 + rr;
            out_idx[grow] = (float)ix;
            if (d2 - d < TAU) {                           // near-tie -> exact recheck
                int p = atomicAdd(cnt, 1);
                if (p < CAP) list[p] = grow;
            }
        }
    }
}

// ---------- K2b: exact fp32 recheck of flagged rows (replicates round-1 math) ----------
__global__ __launch_bounds__(256)
void vq_recheck(const float* __restrict__ x, const float* __restrict__ cn,
                const float* __restrict__ cc, const int* __restrict__ cnt,
                const int* __restrict__ list, float* __restrict__ out_idx) {
    int w = threadIdx.x >> 6, l = threadIdx.x & 63;
    int wid = blockIdx.x * 4 + w, nw = gridDim.x * 4;
    int n = *cnt; if (n > CAP) n = CAP;
    for (int e = wid; e < n; e += nw) {
        int row = list[e];
        float xvr = x[(size_t)row * DIM + l];
        float ss = xvr * xvr;
        #pragma unroll
        for (int off = 32; off; off >>= 1) ss += __shfl_xor(ss, off, 64);
        float inv = 1.0f / fmaxf(sqrtf(ss), EPS);
        float dot[16];
        #pragma unroll
        for (int kk = 0; kk < 16; ++kk) dot[kk] = 0.f;
        for (int d = 0; d < 64; ++d) {
            float xd = __shfl(xvr, d, 64);
            #pragma unroll
            for (int kk = 0; kk < 16; ++kk)
                dot[kk] = fmaf(xd, cn[(size_t)(l + 64 * kk) * DIM + d], dot[kk]);
        }
        float best = INFINITY; int bix = 0x7fffffff;
        #pragma unroll
        for (int kk = 0; kk < 16; ++kk) {
            int k = l + 64 * kk;                       // ascending per lane
            float dist = cc[k] - 2.0f * (inv * dot[kk]);
            if (dist < best) { best = dist; bix = k; }
        }
        #pragma unroll
        for (int off = 1; off < 64; off <<= 1) {
            float ob = __shfl_xor(best, off, 64);
            int   oi = __shfl_xor(bix,  off, 64);
            if (ob < best || (ob == best && oi < bix)) { best = ob; bix = oi; }
        }
        if (l == 0) out_idx[row] = (float)bix;
    }
}

// ---------- K3: gather quantized, write out_q, loss partials ----------
__global__ __launch_bounds__(256)
void vq_gather(const float* __restrict__ x, const float* __restrict__ cb,
               const float* __restrict__ out_idx, float* __restrict__ out_q,
               float* __restrict__ partial) {
    int gid = blockIdx.x * 256 + threadIdx.x;
    int row = gid >> 1, hh = gid & 1;
    int idx = (int)out_idx[row];
    const float4* q4 = (const float4*)(cb + (size_t)idx * DIM + hh * 32);
    const float4* x4 = (const float4*)(x + (size_t)row * DIM + hh * 32);
    float4* o4 = (float4*)out_q + (size_t)row * 16 + hh * 8;
    float ls = 0.f;
    #pragma unroll
    for (int i = 0; i < 8; ++i) {
        float4 q = q4[i], xr = x4[i];
        o4[i] = q;
        float dx = q.x - xr.x, dy = q.y - xr.y, dz = q.z - xr.z, dw = q.w - xr.w;
        ls += dx * dx + dy * dy + dz * dz + dw * dw;
    }
    #pragma unroll
    for (int off = 32; off; off >>= 1) ls += __shfl_xor(ls, off, 64);
    __shared__ float red[4];
    if ((threadIdx.x & 63) == 0) red[threadIdx.x >> 6] = ls;
    __syncthreads();
    if (threadIdx.x == 0) partial[blockIdx.x] = red[0] + red[1] + red[2] + red[3];
}

// ---------- K4: reduce partials -> both losses ----------
__global__ __launch_bounds__(256)
void vq_final(const float* __restrict__ partial, float* __restrict__ out_loss) {
    float s = 0.f;
    for (int i = threadIdx.x; i < 2048; i += 256) s += partial[i];
    #pragma unroll
    for (int off = 32; off; off >>= 1) s += __shfl_xor(s, off, 64);
    __shared__ float red[4];
    if ((threadIdx.x & 63) == 0) red[threadIdx.x >> 6] = s;
    __syncthreads();
    if (threadIdx.x == 0) {
        float t = red[0] + red[1] + red[2] + red[3];
        float m = t / (float)((size_t)N_ROWS * DIM);
        out_loss[0] = m;   // codebook_loss
        out_loss[1] = m;   // commitment_loss (same forward value)
    }
}

extern "C" void kernel_launch(void* const* d_in, const int* in_sizes, int n_in,
                              void* d_out, int out_size, void* d_ws, size_t ws_size,
                              hipStream_t stream) {
    const float* x  = (const float*)d_in[0];   // [262144, 64]
    const float* cb = (const float*)d_in[1];   // [1024, 64]
    float* out = (float*)d_out;
    float* out_q    = out;                               // [N*D]
    float* out_loss = out + (size_t)N_ROWS * DIM;        // [2]
    float* out_idx  = out_loss + 2;                      // [N]

    char* ws = (char*)d_ws;
    float*          cn      = (float*)(ws);              // 262144 B
    float*          cc      = (float*)(ws + 262144);     //   4096 B
    unsigned short* frag    = (unsigned short*)(ws + 266240);  // 262144 B
    int*            cnt     = (int*)(ws + 528384);       //      4 B
    int*            list    = (int*)(ws + 528400);       // 131072 B
    float*          partial = (float*)(ws + 659472);     //   8192 B

    vq_prep   <<<KCODES, 64, 0, stream>>>(cb, cn, cc, frag, cnt);
    vq_mfma   <<<N_ROWS / 128, 256, 0, stream>>>(x, frag, cc, out_idx, cnt, list);
    vq_recheck<<<256, 256, 0, stream>>>(x, cn, cc, cnt, list, out_idx);
    vq_gather <<<N_ROWS / 128, 256, 0, stream>>>(x, cb, out_idx, out_q, partial);
    vq_final  <<<1, 256, 0, stream>>>(partial, out_loss);
}

// Round 3
// 240.306 us; speedup vs baseline: 2.3785x; 1.4947x over previous
//
#include <hip/hip_runtime.h>
#include <math.h>

#define EPS 1e-12f
constexpr int N_ROWS = 262144;
constexpr int KCODES = 1024;
constexpr int DIM    = 64;
constexpr int CAP    = 65536;       // recheck list capacity (~40x expected)
constexpr int CHUNK_SH = 16384;     // shorts per 128-code chunk (hi+lo)

typedef __attribute__((ext_vector_type(8)))  short  short8;
typedef __attribute__((ext_vector_type(16))) float  float16;

__device__ inline unsigned short f2bf(float f) {
    unsigned int u = __float_as_uint(f);
    u = u + 0x7fff + ((u >> 16) & 1);           // RNE
    return (unsigned short)(u >> 16);
}
__device__ inline float bf2f(unsigned short s) {
    return __uint_as_float(((unsigned int)s) << 16);
}

// ---------- K1: normalize codebook -> cc, cnT (transposed), bf16 hi/lo frags ----------
// Frag layout (B-operand, 32x32x16): lane l holds B[k=16s+8*(l>>5)+j][n=32*(4c+t)+(l&31)]
// ushort idx = (((c*4+t)*4+s)*2+p)*512 + lane*8 + j   (p: 0=hi,1=lo)
__global__ __launch_bounds__(64)
void vq_prep(const float* __restrict__ cb, float* __restrict__ cnT,
             float* __restrict__ cc, unsigned short* __restrict__ frag,
             int* __restrict__ cnt, float* __restrict__ dloss) {
    int n = blockIdx.x;      // code
    int d = threadIdx.x;     // dim
    float v = cb[n * DIM + d];
    float s = v * v;
    #pragma unroll
    for (int off = 32; off; off >>= 1) s += __shfl_xor(s, off, 64);
    float vn = v / fmaxf(sqrtf(s), EPS);
    cnT[d * KCODES + n] = vn;                       // transposed for recheck
    float s2 = vn * vn;
    #pragma unroll
    for (int off = 32; off; off >>= 1) s2 += __shfl_xor(s2, off, 64);
    if (d == 0) cc[n] = s2;
    unsigned short hi = f2bf(vn);
    unsigned short lo = f2bf(vn - bf2f(hi));
    int c = n >> 7, t = (n >> 5) & 3;
    int lane = (n & 31) + 32 * ((d >> 3) & 1);
    int si = d >> 4, j = d & 7;
    size_t base = (size_t)(((c * 4 + t) * 4 + si) * 2) * 512 + lane * 8 + j;
    frag[base]       = hi;
    frag[base + 512] = lo;
    if (n == 0 && d == 0) { *cnt = 0; *dloss = 0.f; }
}

// ---------- K2: MFMA distances, packed-key argmin, gather+out_q+loss epilogue ----------
__global__ __launch_bounds__(256, 2)
void vq_mfma(const float* __restrict__ x, const unsigned short* __restrict__ frag,
             const float* __restrict__ cb, float* __restrict__ out_q,
             float* __restrict__ out_idx, int* __restrict__ cnt,
             int* __restrict__ list, float* __restrict__ partial) {
    __shared__ unsigned short Blds[2][CHUNK_SH];   // 64 KB double buffer
    __shared__ int   ridx[256];
    __shared__ float redl[4];

    const int tid = threadIdx.x;
    const int w = tid >> 6, l = tid & 63;
    const int lc = l & 31, h = l >> 5;
    const int row0 = blockIdx.x * 256;

    // --- A: two row-tiles per wave, rows = row0 + w*64 + tile*32 + lc ---
    short8 ahi[2][4], alo[2][4];
    #pragma unroll
    for (int tile = 0; tile < 2; ++tile) {
        int row = row0 + w * 64 + tile * 32 + lc;
        float xv[4][8]; float ss = 0.f;
        #pragma unroll
        for (int s = 0; s < 4; ++s) {
            const float* p = x + (size_t)row * DIM + s * 16 + h * 8;
            float4 a = *(const float4*)p;
            float4 b = *(const float4*)(p + 4);
            xv[s][0]=a.x; xv[s][1]=a.y; xv[s][2]=a.z; xv[s][3]=a.w;
            xv[s][4]=b.x; xv[s][5]=b.y; xv[s][6]=b.z; xv[s][7]=b.w;
            ss += a.x*a.x + a.y*a.y + a.z*a.z + a.w*a.w
                + b.x*b.x + b.y*b.y + b.z*b.z + b.w*b.w;
        }
        ss += __shfl_xor(ss, 32, 64);
        float inv = 1.0f / fmaxf(sqrtf(ss), EPS);
        #pragma unroll
        for (int s = 0; s < 4; ++s)
            #pragma unroll
            for (int j = 0; j < 8; ++j) {
                float v = xv[s][j] * inv;
                unsigned short hb = f2bf(v);
                unsigned short lb = f2bf(v - bf2f(hb));
                ahi[tile][s][j] = (short)hb;
                alo[tile][s][j] = (short)lb;
            }
    }

    int m1[2][16], m2[2][16];
    #pragma unroll
    for (int tile = 0; tile < 2; ++tile)
        #pragma unroll
        for (int r = 0; r < 16; ++r) { m1[tile][r] = 0; m2[tile][r] = 0; }

    // stage chunk 0
    {
        const unsigned short* g = frag + (w * 8) * 512 + l * 8;
        #pragma unroll
        for (int q = 0; q < 8; ++q)
            __builtin_amdgcn_global_load_lds(
                (const __attribute__((address_space(1))) unsigned int*)(g + q * 512),
                (__attribute__((address_space(3))) unsigned int*)&Blds[0][(w * 8 + q) * 512],
                16, 0, 0);
    }

    for (int c = 0; c < 8; ++c) {
        __syncthreads();                     // DMA for buf[c&1] landed ~a full chunk ago
        if (c < 7) {                         // prefetch next chunk into the other buffer
            const unsigned short* g = frag + (size_t)(c + 1) * CHUNK_SH + (w * 8) * 512 + l * 8;
            #pragma unroll
            for (int q = 0; q < 8; ++q)
                __builtin_amdgcn_global_load_lds(
                    (const __attribute__((address_space(1))) unsigned int*)(g + q * 512),
                    (__attribute__((address_space(3))) unsigned int*)&Blds[(c + 1) & 1][(w * 8 + q) * 512],
                    16, 0, 0);
        }
        const unsigned short* B = Blds[c & 1];
        #pragma unroll
        for (int t = 0; t < 4; ++t) {
            short8 bhi[4], blo[4];
            #pragma unroll
            for (int s = 0; s < 4; ++s) {
                bhi[s] = *((const short8*)&B[((t * 4 + s) * 2    ) * 512] + l);
                blo[s] = *((const short8*)&B[((t * 4 + s) * 2 + 1) * 512] + l);
            }
            int vcode = (1023 - c * 128 - t * 32) - lc;   // tie-break: max -> lowest code
            #pragma unroll
            for (int tile = 0; tile < 2; ++tile) {
                float16 acc;
                #pragma unroll
                for (int r = 0; r < 16; ++r) acc[r] = 2.0f;   // bias: acc = 2 + dot > 0
                #pragma unroll
                for (int s = 0; s < 4; ++s) {
                    acc = __builtin_amdgcn_mfma_f32_32x32x16_bf16(ahi[tile][s], bhi[s], acc, 0, 0, 0);
                    acc = __builtin_amdgcn_mfma_f32_32x32x16_bf16(alo[tile][s], bhi[s], acc, 0, 0, 0);
                    acc = __builtin_amdgcn_mfma_f32_32x32x16_bf16(ahi[tile][s], blo[s], acc, 0, 0, 0);
                }
                #pragma unroll
                for (int r = 0; r < 16; ++r) {
                    int k = (__float_as_int(acc[r]) & (int)0xFFFFFC00) | vcode;
                    int t0 = min(m1[tile][r], k);
                    m1[tile][r] = max(m1[tile][r], k);
                    m2[tile][r] = max(m2[tile][r], t0);
                }
            }
        }
    }

    // --- cross-lane merge over the 32 code-lanes (packed keys) ---
    #pragma unroll
    for (int tile = 0; tile < 2; ++tile)
        #pragma unroll
        for (int r = 0; r < 16; ++r) {
            int a = m1[tile][r], b = m2[tile][r];
            #pragma unroll
            for (int off = 1; off < 32; off <<= 1) {
                int oa = __shfl_xor(a, off, 64);
                int ob = __shfl_xor(b, off, 64);
                int nb = max(max(b, ob), min(a, oa));
                a = max(a, oa); b = nb;
            }
            if (lc == 0) {
                int rowl = w * 64 + tile * 32 + (r & 3) + 8 * (r >> 2) + 4 * h;
                ridx[rowl] = 1023 - (a & 1023);
                if (((a >> 10) - (b >> 10)) <= 1) {        // near-tie under truncation
                    int p = atomicAdd(cnt, 1);
                    if (p < CAP) list[p] = row0 + rowl;
                }
            }
        }
    __syncthreads();

    out_idx[row0 + tid] = (float)ridx[tid];

    // --- gather + out_q + loss partial (x re-read is L3-hot) ---
    float lsum = 0.f;
    const float4* cb4 = (const float4*)cb;
    const float4* x4  = (const float4*)x;
    float4*       o4  = (float4*)out_q;
    #pragma unroll
    for (int i = 0; i < 16; ++i) {
        int f = tid + 256 * i;            // 0..4095
        int r = f >> 4, c4 = f & 15;
        float4 q  = cb4[ridx[r] * 16 + c4];
        float4 xr = x4[(size_t)row0 * 16 + f];
        o4[(size_t)row0 * 16 + f] = q;
        float dx = q.x - xr.x, dy = q.y - xr.y, dz = q.z - xr.z, dw = q.w - xr.w;
        lsum += dx * dx + dy * dy + dz * dz + dw * dw;
    }
    #pragma unroll
    for (int off = 32; off; off >>= 1) lsum += __shfl_xor(lsum, off, 64);
    if (l == 0) redl[w] = lsum;
    __syncthreads();
    if (tid == 0) partial[blockIdx.x] = redl[0] + redl[1] + redl[2] + redl[3];
}

// ---------- K3: exact fp32 recheck of flagged rows + patch idx/out_q/loss ----------
__global__ __launch_bounds__(256)
void vq_recheck(const float* __restrict__ x, const float* __restrict__ cnT,
                const float* __restrict__ cc, const float* __restrict__ cb,
                const int* __restrict__ cnt, const int* __restrict__ list,
                float* __restrict__ out_idx, float* __restrict__ out_q,
                float* __restrict__ dloss) {
    int w = threadIdx.x >> 6, l = threadIdx.x & 63;
    int wid = blockIdx.x * 4 + w, nw = gridDim.x * 4;
    int n = *cnt; if (n > CAP) n = CAP;
    for (int e = wid; e < n; e += nw) {
        int row = list[e];
        float xl = x[(size_t)row * DIM + l];
        float ss = xl * xl;
        #pragma unroll
        for (int off = 32; off; off >>= 1) ss += __shfl_xor(ss, off, 64);
        float inv = 1.0f / fmaxf(sqrtf(ss), EPS);
        float dot[16];
        #pragma unroll
        for (int kk = 0; kk < 16; ++kk) dot[kk] = 0.f;
        for (int d = 0; d < 64; ++d) {
            float xd = __shfl(xl, d, 64);
            #pragma unroll
            for (int kk = 0; kk < 16; ++kk)      // lanes consecutive -> coalesced
                dot[kk] = fmaf(xd, cnT[d * KCODES + l + 64 * kk], dot[kk]);
        }
        float best = INFINITY; int bix = 0x7fffffff;
        #pragma unroll
        for (int kk = 0; kk < 16; ++kk) {
            int k = l + 64 * kk;                 // ascending per lane
            float dist = cc[k] - 2.0f * (inv * dot[kk]);
            if (dist < best) { best = dist; bix = k; }
        }
        #pragma unroll
        for (int off = 1; off < 64; off <<= 1) {
            float ob = __shfl_xor(best, off, 64);
            int   oi = __shfl_xor(bix,  off, 64);
            if (ob < best || (ob == best && oi < bix)) { best = ob; bix = oi; }
        }
        int oldi = (int)out_idx[row];
        if (bix != oldi) {
            float qn = cb[(size_t)bix  * DIM + l];
            float qo = cb[(size_t)oldi * DIM + l];
            float an = qn - xl, ao = qo - xl;
            float dl = an * an - ao * ao;
            #pragma unroll
            for (int off = 32; off; off >>= 1) dl += __shfl_xor(dl, off, 64);
            out_q[(size_t)row * DIM + l] = qn;
            if (l == 0) { out_idx[row] = (float)bix; atomicAdd(dloss, dl); }
        }
    }
}

// ---------- K4: reduce partials (+delta) -> both losses ----------
__global__ __launch_bounds__(256)
void vq_final(const float* __restrict__ partial, const float* __restrict__ dloss,
              float* __restrict__ out_loss) {
    float s = 0.f;
    for (int i = threadIdx.x; i < 1024; i += 256) s += partial[i];
    #pragma unroll
    for (int off = 32; off; off >>= 1) s += __shfl_xor(s, off, 64);
    __shared__ float red[4];
    if ((threadIdx.x & 63) == 0) red[threadIdx.x >> 6] = s;
    __syncthreads();
    if (threadIdx.x == 0) {
        float t = red[0] + red[1] + red[2] + red[3] + *dloss;
        float m = t / (float)((size_t)N_ROWS * DIM);
        out_loss[0] = m;   // codebook_loss
        out_loss[1] = m;   // commitment_loss (same forward value)
    }
}

extern "C" void kernel_launch(void* const* d_in, const int* in_sizes, int n_in,
                              void* d_out, int out_size, void* d_ws, size_t ws_size,
                              hipStream_t stream) {
    const float* x  = (const float*)d_in[0];   // [262144, 64]
    const float* cb = (const float*)d_in[1];   // [1024, 64]
    float* out = (float*)d_out;
    float* out_q    = out;                               // [N*D]
    float* out_loss = out + (size_t)N_ROWS * DIM;        // [2]
    float* out_idx  = out_loss + 2;                      // [N]

    char* ws = (char*)d_ws;
    float*          cnT     = (float*)(ws);                    // 262144 B
    float*          cc      = (float*)(ws + 262144);           //   4096 B
    unsigned short* frag    = (unsigned short*)(ws + 266240);  // 262144 B
    int*            cnt     = (int*)(ws + 528384);             //      4 B
    float*          dloss   = (float*)(ws + 528388);           //      4 B
    int*            list    = (int*)(ws + 528400);             // 262144 B
    float*          partial = (float*)(ws + 790544);           //   4096 B

    vq_prep   <<<KCODES, 64, 0, stream>>>(cb, cnT, cc, frag, cnt, dloss);
    vq_mfma   <<<N_ROWS / 256, 256, 0, stream>>>(x, frag, cb, out_q, out_idx, cnt, list, partial);
    vq_recheck<<<512, 256, 0, stream>>>(x, cnT, cc, cb, cnt, list, out_idx, out_q, dloss);
    vq_final  <<<1, 256, 0, stream>>>(partial, dloss, out_loss);
}